// Round 15
// baseline (94.936 us; speedup 1.0000x reference)
//
#include <hip/hip_runtime.h>
#include <math.h>

// Hexagonal sensor photon binning — R14 (resubmit): global_load_lds DMA staging
// + counted vmcnt + raw barriers (T3/T4 pattern). R6-R13 ruled out occupancy,
// VALU count, MLP depth, flush atomics, and (mostly) DRAM locality; all pipes
// <30% busy. Remaining suspect: exposed per-wave vmcnt waits on the
// VGPR-return path. This version stages photon tiles into LDS via
// fire-and-forget DMA; waves never hold load results in VGPRs; counted
// vmcnt(3) keeps the next tile's loads in flight across barriers.
//  * 1280 blocks x 256 threads (5 blocks/CU, LDS 31.8 KB)
//  * tile = 1024 photons (256 f32x4 groups/stream), double-buffered
//  * closed-form hex index, LDS hist, store-flush + rowgroup reduce

typedef float f32x4 __attribute__((ext_vector_type(4)));

#define BIN_BLOCKS  1280
#define BIN_THREADS 256
#define TILE_G      256          // f32x4 groups per tile
#define HIST_F      1808         // hist floats (1801 padded, 16B-aligned)
#define BUF_F       3072         // floats per buffer (3 streams x 1024)
#define RED_GROUP   32

__global__ void hex_zero_kernel(float* __restrict__ p, int n) {
    int i = blockIdx.x * blockDim.x + threadIdx.x;
    if (i < n) p[i] = 0.0f;
}

__global__ __launch_bounds__(256) void hex_reduce_kernel(
    const float* __restrict__ partials, float* __restrict__ out,
    int n_pixels, int nrows)
{
    int pix = blockIdx.x * blockDim.x + threadIdx.x;
    if (pix >= n_pixels) return;
    int r0 = blockIdx.y * RED_GROUP;
    int r1 = min(r0 + RED_GROUP, nrows);
    float s = 0.0f;
    const float* p = partials + (size_t)r0 * n_pixels + pix;
    #pragma unroll 8
    for (int r = r0; r < r1; ++r) {
        s += *p;
        p += n_pixels;
    }
    atomicAdd(&out[pix], s);
}

__global__ __launch_bounds__(BIN_THREADS) void hex_bin_kernel(
    const float* __restrict__ x,
    const float* __restrict__ y,
    const float* __restrict__ vals,
    const float* __restrict__ hex_size_p,
    const float* __restrict__ q_off_p,
    const float* __restrict__ r_off_p,
    const int*   __restrict__ q_min_p,
    const int*   __restrict__ r_min_p,
    int Rh, int n_pixels, int n_photons,
    float* __restrict__ flush_dst,
    int flush_mode)   // 2 = private row store, 0 = direct atomic fallback
{
    extern __shared__ float lds[];   // [HIST_F hist][2 x BUF_F tile buffers]
    for (int i = threadIdx.x; i < HIST_F; i += blockDim.x) lds[i] = 0.0f;
    __syncthreads();

    const float inv_h = 1.0f / hex_size_p[0];
    const float A  = 0.57735026918962576f * inv_h;
    const float Bn = -(0.33333333333333333f * inv_h);
    const float C  = 0.66666666666666667f * inv_h;
    const float qc = -q_off_p[0];
    const float rc = -r_off_p[0];
    const int   qmin = q_min_p[0];
    const int   rmin = r_min_p[0];

    const unsigned twoR = (unsigned)(2 * Rh);
    const int Rp1 = Rh + 1;

    auto process = [&](float xf, float yf, float vf) {
        float q = fmaf(A, xf, fmaf(Bn, yf, qc));
        float r = fmaf(C, yf, rc);
        float t = q + r;                  // s = -t, sr = -rintf(t)
        float qr = rintf(q);
        float rr = rintf(r);
        float tr = rintf(t);
        float qd = fabsf(qr - q);
        float rd = fabsf(rr - r);
        float td = fabsf(tr - t);         // == sd
        float q2 = (qd > rd && qd > td) ? (tr - rr) : qr;
        float r2 = (rd > qd && rd > td) ? (tr - qr) : rr;
        int qi = (int)q2 - qmin;
        int ri = (int)r2 - rmin;
        int d  = qi + ri;
        if ((unsigned)qi <= twoR && (unsigned)ri <= twoR &&
            (unsigned)(d - Rh) <= twoR) {
            int u  = max(qi - Rh, 0);
            int p  = qi * Rp1 + ((qi * qi - qi) >> 1) + d - Rh - u * u;
            atomicAdd(&lds[p], vf);       // ds_add_f32 (no return)
        }
    };

    const int n4 = n_photons >> 2;
    const f32x4* __restrict__ px = (const f32x4*)x;
    const f32x4* __restrict__ py = (const f32x4*)y;
    const f32x4* __restrict__ pv = (const f32x4*)vals;

    const int C4 = (n4 + gridDim.x - 1) / gridDim.x;
    const int g0 = blockIdx.x * C4;
    const int g1 = min(g0 + C4, n4);
    const int Cg = g1 - g0;
    const int T  = (Cg > 0) ? (Cg / TILE_G) : 0;

    const int tid = (int)threadIdx.x;

    // stage tile -> buffer bsel via global_load_lds (lane i writes base+i*16)
    auto stage = [&](int bsel, int tile) {
        int g = g0 + tile * TILE_G + tid;
        int base = HIST_F + bsel * BUF_F + ((tid >> 6) << 8);  // wave-uniform
        int ub = __builtin_amdgcn_readfirstlane(base);
        __builtin_amdgcn_global_load_lds(
            (const __attribute__((address_space(1))) void*)&px[g],
            (__attribute__((address_space(3))) void*)&lds[ub + 0],    16, 0, 0);
        __builtin_amdgcn_global_load_lds(
            (const __attribute__((address_space(1))) void*)&py[g],
            (__attribute__((address_space(3))) void*)&lds[ub + 1024], 16, 0, 0);
        __builtin_amdgcn_global_load_lds(
            (const __attribute__((address_space(1))) void*)&pv[g],
            (__attribute__((address_space(3))) void*)&lds[ub + 2048], 16, 0, 0);
    };

    if (T > 0) {
        stage(0, 0);
        if (T > 1) {
            stage(1, 1);
            asm volatile("s_waitcnt vmcnt(3)" ::: "memory");
        } else {
            asm volatile("s_waitcnt vmcnt(0)" ::: "memory");
        }
        __builtin_amdgcn_sched_barrier(0);
        __builtin_amdgcn_s_barrier();

        for (int t = 0; t < T; ++t) {
            int cur = t & 1;
            int bb = HIST_F + cur * BUF_F + tid * 4;
            f32x4 xa = *(const f32x4*)&lds[bb + 0];
            f32x4 ya = *(const f32x4*)&lds[bb + 1024];
            f32x4 va = *(const f32x4*)&lds[bb + 2048];
            process(xa.x, ya.x, va.x);
            process(xa.y, ya.y, va.y);
            process(xa.z, ya.z, va.z);
            process(xa.w, ya.w, va.w);
            __builtin_amdgcn_s_barrier();          // all readers done with cur
            if (t + 1 < T) {
                if (t + 2 < T) {
                    stage(cur, t + 2);             // overwrite cur for t+2
                    asm volatile("s_waitcnt vmcnt(3)" ::: "memory");
                } else {
                    asm volatile("s_waitcnt vmcnt(0)" ::: "memory");
                }
                __builtin_amdgcn_sched_barrier(0);
                __builtin_amdgcn_s_barrier();      // buf[(t+1)&1] ready
            }
        }
    }

    // leftover groups (Cg % TILE_G) via direct loads
    for (int g = g0 + T * TILE_G + tid; g < g1; g += TILE_G) {
        f32x4 xa = px[g];
        f32x4 ya = py[g];
        f32x4 va = pv[g];
        process(xa.x, ya.x, va.x);
        process(xa.y, ya.y, va.y);
        process(xa.z, ya.z, va.z);
        process(xa.w, ya.w, va.w);
    }

    // photon tail (n_photons % 4)
    {
        int t0 = (n4 << 2) + blockIdx.x * blockDim.x + tid;
        int ts = gridDim.x * blockDim.x;
        for (int t = t0; t < n_photons; t += ts)
            process(x[t], y[t], vals[t]);
    }

    __syncthreads();   // drains vm/lgkm incl. hist atomics
    if (flush_mode == 2) {
        float* dst = flush_dst + (size_t)blockIdx.x * n_pixels;
        for (int k = tid; k < n_pixels; k += blockDim.x)
            dst[k] = lds[k];
    } else {
        for (int k = tid; k < n_pixels; k += blockDim.x) {
            float h = lds[k];
            if (h != 0.0f) atomicAdd(&flush_dst[k], h);
        }
    }
}

extern "C" void kernel_launch(void* const* d_in, const int* in_sizes, int n_in,
                              void* d_out, int out_size, void* d_ws, size_t ws_size,
                              hipStream_t stream) {
    const float* x      = (const float*)d_in[0];
    const float* y      = (const float*)d_in[1];
    const float* vals   = (const float*)d_in[2];
    const float* hexs   = (const float*)d_in[4];
    const float* qoff   = (const float*)d_in[5];
    const float* roff   = (const float*)d_in[6];
    const int*   qmin   = (const int*)d_in[7];
    const int*   rmin   = (const int*)d_in[8];

    const int n_photons = in_sizes[0];
    const int lut_elems = in_sizes[3];
    const int Q  = (int)(0.5 + sqrt((double)lut_elems));  // 49
    const int Rh = (Q - 1) / 2;                           // 24
    const int n_pixels = out_size;

    float* out = (float*)d_out;
    float* partials = (float*)d_ws;

    const size_t lds_bytes = (size_t)(HIST_F + 2 * BUF_F) * sizeof(float); // 31808
    const size_t part_elems = (size_t)BIN_BLOCKS * (size_t)n_pixels;

    if (ws_size >= part_elems * sizeof(float)) {
        hex_zero_kernel<<<(n_pixels + 255) / 256, 256, 0, stream>>>(out, n_pixels);
        hex_bin_kernel<<<BIN_BLOCKS, BIN_THREADS, lds_bytes, stream>>>(
            x, y, vals, hexs, qoff, roff, qmin, rmin,
            Rh, n_pixels, n_photons, partials, 2);
        dim3 rgrid((n_pixels + 255) / 256, BIN_BLOCKS / RED_GROUP);
        hex_reduce_kernel<<<rgrid, 256, 0, stream>>>(
            partials, out, n_pixels, BIN_BLOCKS);
    } else {
        hex_zero_kernel<<<(n_pixels + 255) / 256, 256, 0, stream>>>(out, n_pixels);
        hex_bin_kernel<<<BIN_BLOCKS, BIN_THREADS, lds_bytes, stream>>>(
            x, y, vals, hexs, qoff, roff, qmin, rmin,
            Rh, n_pixels, n_photons, out, 0);
    }
}

// Round 16
// 82.520 us; speedup vs baseline: 1.1505x; 1.1505x over previous
//
#include <hip/hip_runtime.h>
#include <math.h>

// Hexagonal sensor photon binning — R16: R12 (best, 74us) + overhead cuts.
//  * paired 32B/lane loads: 2 adjacent f32x4 groups per thread per iter,
//    2-deep pipeline -> 12 x 16B loads (192B/lane) in flight
//  * no zero kernel, no atomics anywhere in the global flush path:
//    bin blocks fully overwrite private partial rows; reduce kernel writes
//    out[pix] = sum(rows) directly (unroll 16)
//  * block-chunked contiguous walk (512 blocks x 1024 threads), nt loads,
//    closed-form hex index, LDS hist (absmax-0.0 math lineage unchanged)

typedef float f32x4 __attribute__((ext_vector_type(4)));

#define BIN_BLOCKS  512
#define BIN_THREADS 1024

__global__ void hex_zero_kernel(float* __restrict__ p, int n) {
    int i = blockIdx.x * blockDim.x + threadIdx.x;
    if (i < n) p[i] = 0.0f;
}

// direct-write reduce: out[pix] = sum over nrows of partials[r][pix]
__global__ __launch_bounds__(256) void hex_reduce_direct(
    const float* __restrict__ partials, float* __restrict__ out,
    int n_pixels, int nrows)
{
    int pix = blockIdx.x * blockDim.x + threadIdx.x;
    if (pix >= n_pixels) return;
    float s = 0.0f;
    const float* p = partials + pix;
    #pragma unroll 16
    for (int r = 0; r < nrows; ++r) {
        s += *p;
        p += n_pixels;
    }
    out[pix] = s;
}

__global__ __launch_bounds__(BIN_THREADS) void hex_bin_kernel(
    const float* __restrict__ x,
    const float* __restrict__ y,
    const float* __restrict__ vals,
    const float* __restrict__ hex_size_p,
    const float* __restrict__ q_off_p,
    const float* __restrict__ r_off_p,
    const int*   __restrict__ q_min_p,
    const int*   __restrict__ r_min_p,
    int Rh, int n_pixels, int n_photons,
    float* __restrict__ flush_dst,
    int flush_mode)   // 2 = private row store, 0 = direct atomic fallback
{
    extern __shared__ float hist[];  // n_pixels floats
    for (int i = threadIdx.x; i < n_pixels; i += blockDim.x) hist[i] = 0.0f;
    __syncthreads();

    const float inv_h = 1.0f / hex_size_p[0];
    const float A  = 0.57735026918962576f * inv_h;
    const float Bn = -(0.33333333333333333f * inv_h);
    const float C  = 0.66666666666666667f * inv_h;
    const float qc = -q_off_p[0];
    const float rc = -r_off_p[0];
    const int   qmin = q_min_p[0];
    const int   rmin = r_min_p[0];

    const unsigned twoR = (unsigned)(2 * Rh);
    const int Rp1 = Rh + 1;

    auto process = [&](float xf, float yf, float vf) {
        float q = fmaf(A, xf, fmaf(Bn, yf, qc));
        float r = fmaf(C, yf, rc);
        float t = q + r;                  // s = -t, sr = -rintf(t)
        float qr = rintf(q);
        float rr = rintf(r);
        float tr = rintf(t);
        float qd = fabsf(qr - q);
        float rd = fabsf(rr - r);
        float td = fabsf(tr - t);         // == sd
        float q2 = (qd > rd && qd > td) ? (tr - rr) : qr;
        float r2 = (rd > qd && rd > td) ? (tr - qr) : rr;
        int qi = (int)q2 - qmin;
        int ri = (int)r2 - rmin;
        int d  = qi + ri;
        if ((unsigned)qi <= twoR && (unsigned)ri <= twoR &&
            (unsigned)(d - Rh) <= twoR) {
            int u  = max(qi - Rh, 0);
            int p  = qi * Rp1 + ((qi * qi - qi) >> 1) + d - Rh - u * u;
            atomicAdd(&hist[p], vf);      // ds_add_f32 (no return)
        }
    };

    const int n4 = n_photons >> 2;       // f32x4 groups
    const int n8 = n4 >> 1;              // pairs of adjacent groups
    const f32x4* __restrict__ px = (const f32x4*)x;
    const f32x4* __restrict__ py = (const f32x4*)y;
    const f32x4* __restrict__ pv = (const f32x4*)vals;

    // ---- block-chunked contiguous walk over pairs (32B/lane/stream) ----
    const int P  = (n8 + gridDim.x - 1) / gridDim.x;   // pairs per block
    const int j0 = blockIdx.x * P;
    const int j1 = min(j0 + P, n8);
    const int BS = blockDim.x;

    int j = j0 + threadIdx.x;
    f32x4 xa, xb, ya, yb, va, vb;
    if (j < j1) {
        int a = 2 * j, b = a + 1;
        xa = __builtin_nontemporal_load(&px[a]);
        xb = __builtin_nontemporal_load(&px[b]);
        ya = __builtin_nontemporal_load(&py[a]);
        yb = __builtin_nontemporal_load(&py[b]);
        va = __builtin_nontemporal_load(&pv[a]);
        vb = __builtin_nontemporal_load(&pv[b]);
    }
    while (j < j1) {
        int jn = j + BS;
        f32x4 nxa, nxb, nya, nyb, nva, nvb;
        bool has_next = jn < j1;
        if (has_next) {
            int a = 2 * jn, b = a + 1;
            nxa = __builtin_nontemporal_load(&px[a]);
            nxb = __builtin_nontemporal_load(&px[b]);
            nya = __builtin_nontemporal_load(&py[a]);
            nyb = __builtin_nontemporal_load(&py[b]);
            nva = __builtin_nontemporal_load(&pv[a]);
            nvb = __builtin_nontemporal_load(&pv[b]);
        }
        process(xa.x, ya.x, va.x);
        process(xa.y, ya.y, va.y);
        process(xa.z, ya.z, va.z);
        process(xa.w, ya.w, va.w);
        process(xb.x, yb.x, vb.x);
        process(xb.y, yb.y, vb.y);
        process(xb.z, yb.z, vb.z);
        process(xb.w, yb.w, vb.w);
        if (has_next) {
            xa = nxa; xb = nxb; ya = nya; yb = nyb; va = nva; vb = nvb;
        }
        j = jn;
    }

    // leftover: photons not covered by pairs (odd group + N%4 tail)
    {
        int t0 = (n8 << 3) + blockIdx.x * blockDim.x + threadIdx.x;
        int ts = gridDim.x * blockDim.x;
        for (int t = t0; t < n_photons; t += ts)
            process(x[t], y[t], vals[t]);
    }

    __syncthreads();
    if (flush_mode == 2) {
        // private row: coalesced stores, fully overwritten -> no zeroing
        float* dst = flush_dst + (size_t)blockIdx.x * n_pixels;
        for (int k = threadIdx.x; k < n_pixels; k += blockDim.x)
            dst[k] = hist[k];
    } else {
        for (int k = threadIdx.x; k < n_pixels; k += blockDim.x) {
            float h = hist[k];
            if (h != 0.0f) atomicAdd(&flush_dst[k], h);
        }
    }
}

extern "C" void kernel_launch(void* const* d_in, const int* in_sizes, int n_in,
                              void* d_out, int out_size, void* d_ws, size_t ws_size,
                              hipStream_t stream) {
    const float* x      = (const float*)d_in[0];
    const float* y      = (const float*)d_in[1];
    const float* vals   = (const float*)d_in[2];
    const float* hexs   = (const float*)d_in[4];
    const float* qoff   = (const float*)d_in[5];
    const float* roff   = (const float*)d_in[6];
    const int*   qmin   = (const int*)d_in[7];
    const int*   rmin   = (const int*)d_in[8];

    const int n_photons = in_sizes[0];
    const int lut_elems = in_sizes[3];
    const int Q  = (int)(0.5 + sqrt((double)lut_elems));  // 49
    const int Rh = (Q - 1) / 2;                           // 24
    const int n_pixels = out_size;

    float* out = (float*)d_out;
    float* partials = (float*)d_ws;

    const size_t lds_bytes = (size_t)n_pixels * sizeof(float);
    const size_t part_elems = (size_t)BIN_BLOCKS * (size_t)n_pixels;

    if (ws_size >= part_elems * sizeof(float)) {
        // no zero kernel: partial rows fully overwritten, reduce writes out directly
        hex_bin_kernel<<<BIN_BLOCKS, BIN_THREADS, lds_bytes, stream>>>(
            x, y, vals, hexs, qoff, roff, qmin, rmin,
            Rh, n_pixels, n_photons, partials, 2);
        hex_reduce_direct<<<(n_pixels + 255) / 256, 256, 0, stream>>>(
            partials, out, n_pixels, BIN_BLOCKS);
    } else {
        hex_zero_kernel<<<(n_pixels + 255) / 256, 256, 0, stream>>>(out, n_pixels);
        hex_bin_kernel<<<BIN_BLOCKS, BIN_THREADS, lds_bytes, stream>>>(
            x, y, vals, hexs, qoff, roff, qmin, rmin,
            Rh, n_pixels, n_photons, out, 0);
    }
}

// Round 17
// 70.545 us; speedup vs baseline: 1.3457x; 1.1698x over previous
//
#include <hip/hip_runtime.h>
#include <math.h>

// Hexagonal sensor photon binning — R17: R12 bin kernel (best: 68.6us profiled,
// absmax 0.0) + two-stage atomic-free parallel reduce (fixes R16's serial
// 8-block reduce regression).
//  * bin: 512 blocks x 1024 threads, block-chunked contiguous walk, 2-deep SW
//    pipeline, nt 16B loads, closed-form hex index, LDS hist, private-row flush
//  * reduce stage1: 128 blocks, each sums 32 rows -> p2[16][n_pixels] (direct
//    write, no zeroing needed); stage2: 8 blocks sum 16 rows -> out.

typedef float f32x4 __attribute__((ext_vector_type(4)));

#define BIN_BLOCKS  512
#define BIN_THREADS 1024
#define ROWS1       32                      // rows per stage-1 block
#define S1_ROWS     (BIN_BLOCKS / ROWS1)    // 16 intermediate rows

__global__ void hex_zero_kernel(float* __restrict__ p, int n) {
    int i = blockIdx.x * blockDim.x + threadIdx.x;
    if (i < n) p[i] = 0.0f;
}

// stage 1: p2[gy][pix] = sum of partials[gy*ROWS1 .. +ROWS1)[pix]
__global__ __launch_bounds__(256) void hex_reduce_s1(
    const float* __restrict__ partials, float* __restrict__ p2, int n_pixels)
{
    int pix = blockIdx.x * blockDim.x + threadIdx.x;
    if (pix >= n_pixels) return;
    const float* p = partials + (size_t)blockIdx.y * ROWS1 * n_pixels + pix;
    float s = 0.0f;
    #pragma unroll 8
    for (int r = 0; r < ROWS1; ++r) {
        s += *p;
        p += n_pixels;
    }
    p2[(size_t)blockIdx.y * n_pixels + pix] = s;
}

// stage 2: out[pix] = sum of p2[0..S1_ROWS)[pix]
__global__ __launch_bounds__(256) void hex_reduce_s2(
    const float* __restrict__ p2, float* __restrict__ out, int n_pixels)
{
    int pix = blockIdx.x * blockDim.x + threadIdx.x;
    if (pix >= n_pixels) return;
    float s = 0.0f;
    const float* p = p2 + pix;
    #pragma unroll
    for (int r = 0; r < S1_ROWS; ++r) {
        s += *p;
        p += n_pixels;
    }
    out[pix] = s;
}

__global__ __launch_bounds__(BIN_THREADS) void hex_bin_kernel(
    const float* __restrict__ x,
    const float* __restrict__ y,
    const float* __restrict__ vals,
    const float* __restrict__ hex_size_p,
    const float* __restrict__ q_off_p,
    const float* __restrict__ r_off_p,
    const int*   __restrict__ q_min_p,
    const int*   __restrict__ r_min_p,
    int Rh, int n_pixels, int n_photons,
    float* __restrict__ flush_dst,
    int flush_mode)   // 2 = private row store, 0 = direct atomic fallback
{
    extern __shared__ float hist[];  // n_pixels floats
    for (int i = threadIdx.x; i < n_pixels; i += blockDim.x) hist[i] = 0.0f;
    __syncthreads();

    const float inv_h = 1.0f / hex_size_p[0];
    const float A  = 0.57735026918962576f * inv_h;
    const float Bn = -(0.33333333333333333f * inv_h);
    const float C  = 0.66666666666666667f * inv_h;
    const float qc = -q_off_p[0];
    const float rc = -r_off_p[0];
    const int   qmin = q_min_p[0];
    const int   rmin = r_min_p[0];

    const unsigned twoR = (unsigned)(2 * Rh);
    const int Rp1 = Rh + 1;

    auto process = [&](float xf, float yf, float vf) {
        float q = fmaf(A, xf, fmaf(Bn, yf, qc));
        float r = fmaf(C, yf, rc);
        float t = q + r;                  // s = -t, sr = -rintf(t)
        float qr = rintf(q);
        float rr = rintf(r);
        float tr = rintf(t);
        float qd = fabsf(qr - q);
        float rd = fabsf(rr - r);
        float td = fabsf(tr - t);         // == sd
        float q2 = (qd > rd && qd > td) ? (tr - rr) : qr;
        float r2 = (rd > qd && rd > td) ? (tr - qr) : rr;
        int qi = (int)q2 - qmin;
        int ri = (int)r2 - rmin;
        int d  = qi + ri;
        if ((unsigned)qi <= twoR && (unsigned)ri <= twoR &&
            (unsigned)(d - Rh) <= twoR) {
            int u  = max(qi - Rh, 0);
            int p  = qi * Rp1 + ((qi * qi - qi) >> 1) + d - Rh - u * u;
            atomicAdd(&hist[p], vf);      // ds_add_f32 (no return)
        }
    };

    const int n4 = n_photons >> 2;       // 4-photon groups
    const f32x4* __restrict__ px = (const f32x4*)x;
    const f32x4* __restrict__ py = (const f32x4*)y;
    const f32x4* __restrict__ pv = (const f32x4*)vals;

    // ---- block-chunked contiguous walk ----
    const int C4 = (n4 + gridDim.x - 1) / gridDim.x;   // groups per block
    const int g0 = blockIdx.x * C4;
    const int g1 = min(g0 + C4, n4);

    // 2-stage software pipeline over g += blockDim.x
    int g = g0 + threadIdx.x;
    f32x4 xa, ya, va;
    if (g < g1) {
        xa = __builtin_nontemporal_load(&px[g]);
        ya = __builtin_nontemporal_load(&py[g]);
        va = __builtin_nontemporal_load(&pv[g]);
    }
    while (g < g1) {
        int gn = g + blockDim.x;
        f32x4 nx, ny, nv;
        bool has_next = gn < g1;
        if (has_next) {
            nx = __builtin_nontemporal_load(&px[gn]);
            ny = __builtin_nontemporal_load(&py[gn]);
            nv = __builtin_nontemporal_load(&pv[gn]);
        }
        process(xa.x, ya.x, va.x);
        process(xa.y, ya.y, va.y);
        process(xa.z, ya.z, va.z);
        process(xa.w, ya.w, va.w);
        if (has_next) { xa = nx; ya = ny; va = nv; }
        g = gn;
    }

    // photon tail (n_photons % 4)
    {
        int t0 = (n4 << 2) + blockIdx.x * blockDim.x + threadIdx.x;
        int ts = gridDim.x * blockDim.x;
        for (int t = t0; t < n_photons; t += ts)
            process(x[t], y[t], vals[t]);
    }

    __syncthreads();
    if (flush_mode == 2) {
        float* dst = flush_dst + (size_t)blockIdx.x * n_pixels;
        for (int k = threadIdx.x; k < n_pixels; k += blockDim.x)
            dst[k] = hist[k];
    } else {
        for (int k = threadIdx.x; k < n_pixels; k += blockDim.x) {
            float h = hist[k];
            if (h != 0.0f) atomicAdd(&flush_dst[k], h);
        }
    }
}

extern "C" void kernel_launch(void* const* d_in, const int* in_sizes, int n_in,
                              void* d_out, int out_size, void* d_ws, size_t ws_size,
                              hipStream_t stream) {
    const float* x      = (const float*)d_in[0];
    const float* y      = (const float*)d_in[1];
    const float* vals   = (const float*)d_in[2];
    const float* hexs   = (const float*)d_in[4];
    const float* qoff   = (const float*)d_in[5];
    const float* roff   = (const float*)d_in[6];
    const int*   qmin   = (const int*)d_in[7];
    const int*   rmin   = (const int*)d_in[8];

    const int n_photons = in_sizes[0];
    const int lut_elems = in_sizes[3];
    const int Q  = (int)(0.5 + sqrt((double)lut_elems));  // 49
    const int Rh = (Q - 1) / 2;                           // 24
    const int n_pixels = out_size;

    float* out = (float*)d_out;
    float* partials = (float*)d_ws;

    const size_t lds_bytes  = (size_t)n_pixels * sizeof(float);
    const size_t part_elems = (size_t)BIN_BLOCKS * (size_t)n_pixels;
    const size_t p2_elems   = (size_t)S1_ROWS * (size_t)n_pixels;

    if (ws_size >= (part_elems + p2_elems) * sizeof(float)) {
        float* p2 = partials + part_elems;
        hex_bin_kernel<<<BIN_BLOCKS, BIN_THREADS, lds_bytes, stream>>>(
            x, y, vals, hexs, qoff, roff, qmin, rmin,
            Rh, n_pixels, n_photons, partials, 2);
        dim3 g1((n_pixels + 255) / 256, BIN_BLOCKS / ROWS1);
        hex_reduce_s1<<<g1, 256, 0, stream>>>(partials, p2, n_pixels);
        hex_reduce_s2<<<(n_pixels + 255) / 256, 256, 0, stream>>>(
            p2, out, n_pixels);
    } else {
        hex_zero_kernel<<<(n_pixels + 255) / 256, 256, 0, stream>>>(out, n_pixels);
        hex_bin_kernel<<<BIN_BLOCKS, BIN_THREADS, lds_bytes, stream>>>(
            x, y, vals, hexs, qoff, roff, qmin, rmin,
            Rh, n_pixels, n_photons, out, 0);
    }
}